// Round 11
// baseline (570.559 us; speedup 1.0000x reference)
//
#include <hip/hip_runtime.h>
#include <math.h>

#define NEG_SLOPE 0.2f
#define NBMAX 512   // max buckets (N/128); N=50000 -> 391
#define BCAP 4608   // max edges per bucket held in LDS (mean 2048, sigma ~45)

typedef short bf16x8 __attribute__((ext_vector_type(8)));
typedef float f32x4 __attribute__((ext_vector_type(4)));

__device__ __forceinline__ unsigned short f32_to_bf16_rne(float x) {
  unsigned int u = __float_as_uint(x);
  unsigned int r = u + 0x7FFFu + ((u >> 16) & 1u);
  return (unsigned short)(r >> 16);
}
__device__ __forceinline__ float bf16_bits_to_f32(unsigned short h) {
  return __uint_as_float((unsigned int)h << 16);
}
__device__ __forceinline__ void decode8(uint4 v, float* f) {
  f[0] = __uint_as_float(v.x << 16);
  f[1] = __uint_as_float(v.x & 0xFFFF0000u);
  f[2] = __uint_as_float(v.y << 16);
  f[3] = __uint_as_float(v.y & 0xFFFF0000u);
  f[4] = __uint_as_float(v.z << 16);
  f[5] = __uint_as_float(v.z & 0xFFFF0000u);
  f[6] = __uint_as_float(v.w << 16);
  f[7] = __uint_as_float(v.w & 0xFFFF0000u);
}

// ---------------- CSR build, bucketed (round-11 rework) ----------------
// Old per-node scatter had 16x write amplification (WRITE_SIZE 52MB for a 3.2MB
// array): 50k cursors -> whole-array active write front -> dirty-line thrash.
// New: 391 buckets of 128 nodes; bucket writes are address-sequential in time
// (active front ~391 lines, L2-resident, lines fill before eviction).

__global__ __launch_bounds__(256) void bucket_hist_kernel(const int* __restrict__ dst,
                                                          int* __restrict__ bcnt,
                                                          int E, int NB) {
  __shared__ int lh[NBMAX];
  for (int j = threadIdx.x; j < NBMAX; j += 256) lh[j] = 0;
  __syncthreads();
  int stride = gridDim.x * 256;
  for (int i = blockIdx.x * 256 + threadIdx.x; i < E; i += stride)
    atomicAdd(&lh[dst[i] >> 7], 1);
  __syncthreads();
  for (int j = threadIdx.x; j < NB; j += 256) {
    int v = lh[j];
    if (v) atomicAdd(&bcnt[j], v);
  }
}

__global__ __launch_bounds__(512) void bucket_scan_kernel(const int* __restrict__ bcnt,
                                                          int* __restrict__ bbase,
                                                          int* __restrict__ bcursor,
                                                          int* __restrict__ row_start,
                                                          int NB, int Nn, int E) {
  __shared__ int buf[512];
  int t = threadIdx.x;
  int v = (t < NB) ? bcnt[t] : 0;
  buf[t] = v;
  __syncthreads();
  for (int off = 1; off < 512; off <<= 1) {
    int x = (t >= off) ? buf[t - off] : 0;
    __syncthreads();
    buf[t] += x;
    __syncthreads();
  }
  if (t < NB) { int ex = buf[t] - v; bbase[t] = ex; bcursor[t] = ex; }
  if (t == 0) { bbase[NB] = E; row_start[Nn] = E; }
}

// pack: src in bits 0..15 (N < 65536), dst&127 in bits 16..22
__global__ void pair_scatter_kernel(const int* __restrict__ dst, const int* __restrict__ src,
                                    int* __restrict__ bcursor, unsigned* __restrict__ pairs,
                                    int E) {
  int i = blockIdx.x * blockDim.x + threadIdx.x;
  if (i < E) {
    int d = dst[i];
    int p = atomicAdd(&bcursor[d >> 7], 1);
    pairs[p] = (unsigned)src[i] | ((unsigned)(d & 127) << 16);
  }
}

// one block per bucket: LDS counting-sort by local dst, coalesced emit
__global__ __launch_bounds__(256) void csr_build_kernel(const unsigned* __restrict__ pairs,
                                                        const int* __restrict__ bbase,
                                                        int* __restrict__ row_start,
                                                        int* __restrict__ src_sorted, int Nn) {
  __shared__ unsigned pl[BCAP];
  __shared__ int ss[BCAP];
  __shared__ int hist[128], off[128], cur[128];
  const int b = blockIdx.x;
  const int base = bbase[b];
  int cnt = bbase[b + 1] - base;
  if (cnt > BCAP) cnt = BCAP;  // statistically impossible for this input; OOB guard
  const int t = threadIdx.x;
  for (int j = t; j < 128; j += 256) hist[j] = 0;
  __syncthreads();
  for (int i = t; i < cnt; i += 256) {
    unsigned v = pairs[base + i];
    pl[i] = v;
    atomicAdd(&hist[v >> 16], 1);
  }
  __syncthreads();
  if (t < 128) off[t] = hist[t];
  __syncthreads();
  for (int o = 1; o < 128; o <<= 1) {
    int x = (t < 128 && t >= o) ? off[t - o] : 0;
    __syncthreads();
    if (t < 128) off[t] += x;
    __syncthreads();
  }
  if (t < 128) {
    int ex = off[t] - hist[t];               // exclusive within bucket
    cur[t] = ex;
    int node = b * 128 + t;
    if (node < Nn) row_start[node] = base + ex;
  }
  __syncthreads();
  for (int i = t; i < cnt; i += 256) {
    unsigned v = pl[i];
    int q = atomicAdd(&cur[v >> 16], 1);
    ss[q] = (int)(v & 0xFFFFu);
  }
  __syncthreads();
  for (int i = t; i < cnt; i += 256) src_sorted[base + i] = ss[i];
}

// ---------------- weight fragment pre-pack (hi/lo bf16, MFMA B-operand order) ----------------
// B-frag layout for mfma_f32_16x16x32_bf16: lane l holds col = l&15, k = (l>>4)*8 + j.
// Buffer layout: [mat(4)][ks(4)][nb(8)][lane(64)][j(8)]  (16B per lane -> coalesced frag loads)
__global__ void wfrag_kernel(const float* __restrict__ W0, const float* __restrict__ W1,
                             const float* __restrict__ W2, const float* __restrict__ W3,
                             unsigned short* __restrict__ hi, unsigned short* __restrict__ lo) {
  int t = blockIdx.x * 256 + threadIdx.x;  // 4 * 2048
  if (t >= 4 * 2048) return;
  int mat = t >> 11;
  int u = t & 2047;
  int l = u & 63, nb = (u >> 6) & 7, ks = u >> 9;
  const float* W = mat == 0 ? W0 : mat == 1 ? W1 : mat == 2 ? W2 : W3;
  int col = nb * 16 + (l & 15);
  int k0 = ks * 32 + ((l >> 4) << 3);
  unsigned short hv[8], lv[8];
#pragma unroll
  for (int j = 0; j < 8; j++) {
    float x = W[(size_t)(k0 + j) * 128 + col];
    unsigned short h = f32_to_bf16_rne(x);
    hv[j] = h;
    lv[j] = f32_to_bf16_rne(x - bf16_bits_to_f32(h));
  }
  size_t o = (size_t)t * 8;
#pragma unroll
  for (int j = 0; j < 8; j++) { hi[o + j] = hv[j]; lo[o + j] = lv[j]; }
}

// ---------------- dual GEMM via 3xBF16 MFMA ----------------
// P[M,128] = A@Ws + bs ; Q[M,128] = A@Wd + bd.  A fp32, split to hi/lo bf16 in-register.
// Outputs stored as bf16 (RNE after fp32 bias add).
__global__ __launch_bounds__(256) void gemm_mfma_dual(
    const float* __restrict__ A,
    const unsigned short* __restrict__ FSh, const unsigned short* __restrict__ FSl,
    const unsigned short* __restrict__ FDh, const unsigned short* __restrict__ FDl,
    const float* __restrict__ bs_, const float* __restrict__ bd_,
    unsigned short* __restrict__ P, unsigned short* __restrict__ Q, int M) {
  const int tid = (int)threadIdx.x;
  const int w = tid >> 6;
  const int l = tid & 63;
  const int r0 = blockIdx.x * 64 + w * 16;
  const int arow = r0 + (l & 15);          // A-frag: row = lane&15
  const int koff = (l >> 4) << 3;          // A/B-frag: k = (lane>>4)*8 + j
  f32x4 accP[8] = {{0.f, 0.f, 0.f, 0.f}};
  f32x4 accQ[8] = {{0.f, 0.f, 0.f, 0.f}};
#pragma unroll
  for (int nb = 1; nb < 8; nb++) { accP[nb] = accP[0]; accQ[nb] = accQ[0]; }
  const bf16x8* fsh = (const bf16x8*)FSh;
  const bf16x8* fsl = (const bf16x8*)FSl;
  const bf16x8* fdh = (const bf16x8*)FDh;
  const bf16x8* fdl = (const bf16x8*)FDl;
#pragma unroll
  for (int ks = 0; ks < 4; ks++) {
    bf16x8 ahi, alo;
    if (arow < M) {
      const float* ap = A + (size_t)arow * 128 + ks * 32 + koff;
      float4 v0 = *(const float4*)ap;
      float4 v1 = *(const float4*)(ap + 4);
      float va[8] = {v0.x, v0.y, v0.z, v0.w, v1.x, v1.y, v1.z, v1.w};
#pragma unroll
      for (int j = 0; j < 8; j++) {
        unsigned short h = f32_to_bf16_rne(va[j]);
        ahi[j] = (short)h;
        alo[j] = (short)f32_to_bf16_rne(va[j] - bf16_bits_to_f32(h));
      }
    } else {
#pragma unroll
      for (int j = 0; j < 8; j++) { ahi[j] = 0; alo[j] = 0; }
    }
#pragma unroll
    for (int nb = 0; nb < 8; nb++) {
      int fi = (ks * 8 + nb) * 64 + l;
      bf16x8 bsh = fsh[fi];
      bf16x8 bsl = fsl[fi];
      bf16x8 bdh = fdh[fi];
      bf16x8 bdl = fdl[fi];
      accP[nb] = __builtin_amdgcn_mfma_f32_16x16x32_bf16(ahi, bsh, accP[nb], 0, 0, 0);
      accP[nb] = __builtin_amdgcn_mfma_f32_16x16x32_bf16(alo, bsh, accP[nb], 0, 0, 0);
      accP[nb] = __builtin_amdgcn_mfma_f32_16x16x32_bf16(ahi, bsl, accP[nb], 0, 0, 0);
      accQ[nb] = __builtin_amdgcn_mfma_f32_16x16x32_bf16(ahi, bdh, accQ[nb], 0, 0, 0);
      accQ[nb] = __builtin_amdgcn_mfma_f32_16x16x32_bf16(alo, bdh, accQ[nb], 0, 0, 0);
      accQ[nb] = __builtin_amdgcn_mfma_f32_16x16x32_bf16(ahi, bdl, accQ[nb], 0, 0, 0);
    }
  }
  // D-frag: col = lane&15, row = (lane>>4)*4 + reg   [m89-verified mapping]
  const int rbase = r0 + ((l >> 4) << 2);
  const int cl = l & 15;
#pragma unroll
  for (int nb = 0; nb < 8; nb++) {
    int col = nb * 16 + cl;
    float bP = bs_[col], bQ = bd_[col];
#pragma unroll
    for (int r = 0; r < 4; r++) {
      int grow = rbase + r;
      if (grow < M) {
        P[(size_t)grow * 128 + col] = f32_to_bf16_rne(accP[nb][r] + bP);
        Q[(size_t)grow * 128 + col] = f32_to_bf16_rne(accQ[nb][r] + bQ);
      }
    }
  }
}

// ---------------- GATv2 aggregation ----------------
// One wave per dst node, 4 edges per wave-step.
// lane = (es = lane>>4: edge slot 0..3, ls = lane&15: dim-lane).
// Lane owns dims ls*8..ls*8+7 (head = ls>>2) of its slot's edge: one dwordx4
// gather covers a full 256B feature row per slot (4 edges per VMEM instr).
// Per-slot online softmax (m init -1e30; invalid edges t=-2e30 -> ex=0, sc=1),
// flash-merged across slots at the end via xor-16/32 butterfly.
__global__ __launch_bounds__(256, 4) void gat_agg_kernel(
    const unsigned short* __restrict__ P,  // fs bf16 [N,128]
    const unsigned short* __restrict__ Q,  // fd bf16 [N,128]
    const float* __restrict__ attn,        // [128] = [H=4][D=32]
    const int* __restrict__ row_start,
    const int* __restrict__ src_sorted,
    float* __restrict__ out, int N, int do_relu) {
  int wave = (int)((blockIdx.x * blockDim.x + threadIdx.x) >> 6);
  int lane = (int)(threadIdx.x & 63);
  if (wave >= N) return;
  const int es = lane >> 4;
  const int ls = lane & 15;

  float fd[8], av[8];
  decode8(*(const uint4*)&Q[(size_t)wave * 128 + ls * 8], fd);
  {
    float4 A0 = *(const float4*)&attn[ls * 8];
    float4 A1 = *(const float4*)&attn[ls * 8 + 4];
    av[0] = A0.x; av[1] = A0.y; av[2] = A0.z; av[3] = A0.w;
    av[4] = A1.x; av[5] = A1.y; av[6] = A1.z; av[7] = A1.w;
  }
  const int s0 = row_start[wave], s1 = row_start[wave + 1];

  float m = -1e30f, den = 0.f;
  float acc[8];
#pragma unroll
  for (int d = 0; d < 8; d++) acc[d] = 0.f;

  // pipeline prologue: idx+row of chunk 0, idx of chunk 1
  int i0 = s0 + es;
  int idx_c = (i0 < s1) ? src_sorted[i0] : 0;
  uint4 row_n = *(const uint4*)&P[(size_t)idx_c * 128 + ls * 8];
  int i1 = i0 + 4;
  int idx_n = (i1 < s1) ? src_sorted[i1] : 0;

#pragma unroll 1
  for (int base = s0; base < s1; base += 4) {
    uint4 row = row_n;
    // issue row gather for chunk c+1 (idx already resolved)
    row_n = *(const uint4*)&P[(size_t)idx_n * 128 + ls * 8];
    // load idx for chunk c+2
    int i2 = base + 8 + es;
    idx_n = (i2 < s1) ? src_sorted[i2] : 0;
    // compute chunk c
    float c[8];
    decode8(row, c);
    float t = 0.f;
#pragma unroll
    for (int d = 0; d < 8; d++) {
      float x = c[d] + fd[d];
      x = fmaxf(x, NEG_SLOPE * x);          // exact leaky_relu for slope<1
      t = fmaf(x, av[d], t);
    }
    t += __shfl_xor(t, 1);                  // reduce over the head's 4 lanes
    t += __shfl_xor(t, 2);
    t = (base + es < s1) ? t : -2e30f;      // invalid slot -> ex=0, sc=1
    float mn = fmaxf(m, t);
    float sc = __expf(m - mn);
    float ex = __expf(t - mn);
    den = den * sc + ex;
#pragma unroll
    for (int d = 0; d < 8; d++) acc[d] = fmaf(acc[d], sc, ex * c[d]);
    m = mn;
  }

  // flash-merge the 4 slots (lanes differing in bits 4,5 share ls -> same dims/head)
  float M2 = m;
  M2 = fmaxf(M2, __shfl_xor(M2, 16));
  M2 = fmaxf(M2, __shfl_xor(M2, 32));
  float sc = __expf(m - M2);                // empty slot: exp(-1e30-M2)=0 (M2 finite)
  den *= sc;
#pragma unroll
  for (int d = 0; d < 8; d++) acc[d] *= sc;
  den += __shfl_xor(den, 16);
  den += __shfl_xor(den, 32);
#pragma unroll
  for (int d = 0; d < 8; d++) {
    acc[d] += __shfl_xor(acc[d], 16);
    acc[d] += __shfl_xor(acc[d], 32);
  }

  if (es == 0) {
    float invd = (s1 > s0) ? 1.f / den : 0.f;
    float o[8];
#pragma unroll
    for (int d = 0; d < 8; d++) {
      o[d] = acc[d] * invd;
      if (do_relu) o[d] = fmaxf(o[d], 0.f);
    }
    float* op = out + (size_t)wave * 128 + ls * 8;
    *(float4*)op = make_float4(o[0], o[1], o[2], o[3]);
    *(float4*)(op + 4) = make_float4(o[4], o[5], o[6], o[7]);
  }
}

// ---------------- link-prediction scores: one wave per query ----------------
__global__ __launch_bounds__(256) void edge_score_kernel(
    const float* __restrict__ H, const int* __restrict__ qs, const int* __restrict__ qd,
    float* __restrict__ out, int NQ) {
  int wave = (int)((blockIdx.x * blockDim.x + threadIdx.x) >> 6);
  int lane = (int)(threadIdx.x & 63);
  if (wave >= NQ) return;
  int a = qs[wave], b = qd[wave];
  float2 x = *(const float2*)&H[(size_t)a * 128 + lane * 2];
  float2 y = *(const float2*)&H[(size_t)b * 128 + lane * 2];
  float t = x.x * y.x + x.y * y.y;
#pragma unroll
  for (int mask = 1; mask < 64; mask <<= 1) t += __shfl_xor(t, mask, 64);
  if (lane == 0) out[wave] = 1.f / (1.f + __expf(-t));
}

// ---------------- launch ----------------
extern "C" void kernel_launch(void* const* d_in, const int* in_sizes, int n_in,
                              void* d_out, int out_size, void* d_ws, size_t ws_size,
                              hipStream_t stream) {
  const float* feat  = (const float*)d_in[0];
  const int*   esrc  = (const int*)d_in[1];
  const int*   edst  = (const int*)d_in[2];
  const int*   qsrc  = (const int*)d_in[3];
  const int*   qdst  = (const int*)d_in[4];
  const float* W1s   = (const float*)d_in[5];
  const float* b1s   = (const float*)d_in[6];
  const float* W1d   = (const float*)d_in[7];
  const float* b1d   = (const float*)d_in[8];
  const float* attn1 = (const float*)d_in[9];
  const float* W2s   = (const float*)d_in[10];
  const float* b2s   = (const float*)d_in[11];
  const float* W2d   = (const float*)d_in[12];
  const float* b2d   = (const float*)d_in[13];
  const float* attn2 = (const float*)d_in[14];
  float* out = (float*)d_out;

  const int N  = in_sizes[0] / 128;
  const int E  = in_sizes[1];
  const int NQ = in_sizes[3];
  const int NB = (N + 127) >> 7;   // 391 buckets

  char* p = (char*)d_ws;
  auto alloc = [&](size_t bytes) -> char* {
    char* r = p;
    p += (bytes + 255) & ~(size_t)255;
    return r;
  };
  unsigned short* P = (unsigned short*)alloc((size_t)N * 128 * 2);  // bf16
  unsigned short* Q = (unsigned short*)alloc((size_t)N * 128 * 2);  // bf16
  float* H          = (float*)alloc((size_t)N * 128 * 4);
  int*   row_start  = (int*)alloc((size_t)(N + 1) * 4);
  int*   src_sorted = (int*)alloc((size_t)E * 4);
  unsigned* pairs   = (unsigned*)alloc((size_t)E * 4);
  int*   bcnt       = (int*)alloc((size_t)(NBMAX + 1) * 4);
  int*   bbase      = (int*)alloc((size_t)(NBMAX + 1) * 4);
  int*   bcursor    = (int*)alloc((size_t)NBMAX * 4);
  unsigned short* FBhi = (unsigned short*)alloc(4 * 2048 * 8 * 2);  // 128KB
  unsigned short* FBlo = (unsigned short*)alloc(4 * 2048 * 8 * 2);

  // weight fragment pre-pack (independent of graph build)
  wfrag_kernel<<<32, 256, 0, stream>>>(W1s, W1d, W2s, W2d, FBhi, FBlo);

  // CSR build, bucketed (edges grouped by dst; within-node order arbitrary — sums only)
  hipMemsetAsync(bcnt, 0, (size_t)(NBMAX + 1) * 4, stream);
  bucket_hist_kernel<<<512, 256, 0, stream>>>(edst, bcnt, E, NB);
  bucket_scan_kernel<<<1, 512, 0, stream>>>(bcnt, bbase, bcursor, row_start, NB, N, E);
  pair_scatter_kernel<<<(E + 255) / 256, 256, 0, stream>>>(edst, esrc, bcursor, pairs, E);
  csr_build_kernel<<<NB, 256, 0, stream>>>(pairs, bbase, row_start, src_sorted, N);

  const int gblocks = (N + 63) / 64;
  const int per_mat = 2048 * 8;  // ushorts per matrix in FB buffers

  // layer 1
  gemm_mfma_dual<<<gblocks, 256, 0, stream>>>(
      feat, FBhi + 0 * per_mat, FBlo + 0 * per_mat, FBhi + 1 * per_mat, FBlo + 1 * per_mat,
      b1s, b1d, P, Q, N);
  gat_agg_kernel<<<(N + 3) / 4, 256, 0, stream>>>(P, Q, attn1, row_start, src_sorted, H, N, 1);

  // layer 2
  gemm_mfma_dual<<<gblocks, 256, 0, stream>>>(
      H, FBhi + 2 * per_mat, FBlo + 2 * per_mat, FBhi + 3 * per_mat, FBlo + 3 * per_mat,
      b2s, b2d, P, Q, N);
  gat_agg_kernel<<<(N + 3) / 4, 256, 0, stream>>>(P, Q, attn2, row_start, src_sorted, H, N, 0);

  // scores
  edge_score_kernel<<<(NQ + 3) / 4, 256, 0, stream>>>(H, qsrc, qdst, out, NQ);
}

// Round 12
// 311.182 us; speedup vs baseline: 1.8335x; 1.8335x over previous
//
#include <hip/hip_runtime.h>
#include <math.h>

#define NEG_SLOPE 0.2f
#define NBMAX 512   // max buckets (N/128); N=50000 -> 391
#define BCAP 4608   // max edges per bucket held in LDS (mean 2048, sigma ~45)

typedef short bf16x8 __attribute__((ext_vector_type(8)));
typedef float f32x4 __attribute__((ext_vector_type(4)));

__device__ __forceinline__ unsigned short f32_to_bf16_rne(float x) {
  unsigned int u = __float_as_uint(x);
  unsigned int r = u + 0x7FFFu + ((u >> 16) & 1u);
  return (unsigned short)(r >> 16);
}
__device__ __forceinline__ float bf16_bits_to_f32(unsigned short h) {
  return __uint_as_float((unsigned int)h << 16);
}
__device__ __forceinline__ void decode8(uint4 v, float* f) {
  f[0] = __uint_as_float(v.x << 16);
  f[1] = __uint_as_float(v.x & 0xFFFF0000u);
  f[2] = __uint_as_float(v.y << 16);
  f[3] = __uint_as_float(v.y & 0xFFFF0000u);
  f[4] = __uint_as_float(v.z << 16);
  f[5] = __uint_as_float(v.z & 0xFFFF0000u);
  f[6] = __uint_as_float(v.w << 16);
  f[7] = __uint_as_float(v.w & 0xFFFF0000u);
}

// ---------------- CSR build, bucketed (round-12: block-staged reservation) ----------------
// Round-11 post-mortem: per-edge global atomics on 391 cursors = 2046-deep
// same-address chains at ~137ns each -> 281us. Fix: per-block LDS histogram,
// ONE global atomicAdd per (block,bucket) to reserve a range (chain <= #blocks),
// then LDS-cursor placement. (block,bucket) regions are ~64B contiguous ->
// write amplification ~1.

__global__ __launch_bounds__(256) void bucket_hist_kernel(const int* __restrict__ dst,
                                                          int* __restrict__ bcnt,
                                                          int E, int NB) {
  __shared__ int lh[NBMAX];
  for (int j = threadIdx.x; j < NBMAX; j += 256) lh[j] = 0;
  __syncthreads();
  int stride = gridDim.x * 256;
  for (int i = blockIdx.x * 256 + threadIdx.x; i < E; i += stride)
    atomicAdd(&lh[dst[i] >> 7], 1);
  __syncthreads();
  for (int j = threadIdx.x; j < NB; j += 256) {
    int v = lh[j];
    if (v) atomicAdd(&bcnt[j], v);
  }
}

__global__ __launch_bounds__(512) void bucket_scan_kernel(const int* __restrict__ bcnt,
                                                          int* __restrict__ bbase,
                                                          int* __restrict__ bcursor,
                                                          int* __restrict__ row_start,
                                                          int NB, int Nn, int E) {
  __shared__ int buf[512];
  int t = threadIdx.x;
  int v = (t < NB) ? bcnt[t] : 0;
  buf[t] = v;
  __syncthreads();
  for (int off = 1; off < 512; off <<= 1) {
    int x = (t >= off) ? buf[t - off] : 0;
    __syncthreads();
    buf[t] += x;
    __syncthreads();
  }
  if (t < NB) { int ex = buf[t] - v; bbase[t] = ex; bcursor[t] = ex; }
  if (t == 0) { bbase[NB] = E; row_start[Nn] = E; }
}

// pack: src in bits 0..15 (N < 65536), dst&127 in bits 16..22
__global__ __launch_bounds__(256) void pair_scatter_kernel(
    const int* __restrict__ dst, const int* __restrict__ src,
    int* __restrict__ bcursor, unsigned* __restrict__ pairs, int E, int NB) {
  __shared__ int lh[NBMAX];   // phase1: per-block hist; phase3: local cursor
  __shared__ int gb[NBMAX];   // reserved global base per bucket
  const int t = (int)threadIdx.x;
  const int epb = (E + (int)gridDim.x - 1) / (int)gridDim.x;
  const int c0 = (int)blockIdx.x * epb;
  const int c1 = min(c0 + epb, E);
  for (int j = t; j < NBMAX; j += 256) lh[j] = 0;
  __syncthreads();
  for (int i = c0 + t; i < c1; i += 256)
    atomicAdd(&lh[dst[i] >> 7], 1);
  __syncthreads();
  for (int j = t; j < NB; j += 256) {
    int c = lh[j];
    gb[j] = c ? atomicAdd(&bcursor[j], c) : 0;  // one global atomic per (block,bucket)
    lh[j] = 0;                                   // reuse as local cursor
  }
  __syncthreads();
  for (int i = c0 + t; i < c1; i += 256) {
    int d = dst[i];
    int b = d >> 7;
    int p = gb[b] + atomicAdd(&lh[b], 1);        // LDS atomic, cheap
    pairs[p] = (unsigned)src[i] | ((unsigned)(d & 127) << 16);
  }
}

// one block per bucket: LDS counting-sort by local dst, coalesced emit
__global__ __launch_bounds__(256) void csr_build_kernel(const unsigned* __restrict__ pairs,
                                                        const int* __restrict__ bbase,
                                                        int* __restrict__ row_start,
                                                        int* __restrict__ src_sorted, int Nn) {
  __shared__ unsigned pl[BCAP];
  __shared__ int ss[BCAP];
  __shared__ int hist[128], off[128], cur[128];
  const int b = blockIdx.x;
  const int base = bbase[b];
  int cnt = bbase[b + 1] - base;
  if (cnt > BCAP) cnt = BCAP;  // statistically impossible for this input; OOB guard
  const int t = threadIdx.x;
  for (int j = t; j < 128; j += 256) hist[j] = 0;
  __syncthreads();
  for (int i = t; i < cnt; i += 256) {
    unsigned v = pairs[base + i];
    pl[i] = v;
    atomicAdd(&hist[v >> 16], 1);
  }
  __syncthreads();
  if (t < 128) off[t] = hist[t];
  __syncthreads();
  for (int o = 1; o < 128; o <<= 1) {
    int x = (t < 128 && t >= o) ? off[t - o] : 0;
    __syncthreads();
    if (t < 128) off[t] += x;
    __syncthreads();
  }
  if (t < 128) {
    int ex = off[t] - hist[t];               // exclusive within bucket
    cur[t] = ex;
    int node = b * 128 + t;
    if (node < Nn) row_start[node] = base + ex;
  }
  __syncthreads();
  for (int i = t; i < cnt; i += 256) {
    unsigned v = pl[i];
    int q = atomicAdd(&cur[v >> 16], 1);
    ss[q] = (int)(v & 0xFFFFu);
  }
  __syncthreads();
  for (int i = t; i < cnt; i += 256) src_sorted[base + i] = ss[i];
}

// ---------------- weight fragment pre-pack (hi/lo bf16, MFMA B-operand order) ----------------
// B-frag layout for mfma_f32_16x16x32_bf16: lane l holds col = l&15, k = (l>>4)*8 + j.
// Buffer layout: [mat(4)][ks(4)][nb(8)][lane(64)][j(8)]  (16B per lane -> coalesced frag loads)
__global__ void wfrag_kernel(const float* __restrict__ W0, const float* __restrict__ W1,
                             const float* __restrict__ W2, const float* __restrict__ W3,
                             unsigned short* __restrict__ hi, unsigned short* __restrict__ lo) {
  int t = blockIdx.x * 256 + threadIdx.x;  // 4 * 2048
  if (t >= 4 * 2048) return;
  int mat = t >> 11;
  int u = t & 2047;
  int l = u & 63, nb = (u >> 6) & 7, ks = u >> 9;
  const float* W = mat == 0 ? W0 : mat == 1 ? W1 : mat == 2 ? W2 : W3;
  int col = nb * 16 + (l & 15);
  int k0 = ks * 32 + ((l >> 4) << 3);
  unsigned short hv[8], lv[8];
#pragma unroll
  for (int j = 0; j < 8; j++) {
    float x = W[(size_t)(k0 + j) * 128 + col];
    unsigned short h = f32_to_bf16_rne(x);
    hv[j] = h;
    lv[j] = f32_to_bf16_rne(x - bf16_bits_to_f32(h));
  }
  size_t o = (size_t)t * 8;
#pragma unroll
  for (int j = 0; j < 8; j++) { hi[o + j] = hv[j]; lo[o + j] = lv[j]; }
}

// ---------------- dual GEMM via 3xBF16 MFMA ----------------
// P[M,128] = A@Ws + bs ; Q[M,128] = A@Wd + bd.  A fp32, split to hi/lo bf16 in-register.
// Outputs stored as bf16 (RNE after fp32 bias add).
__global__ __launch_bounds__(256) void gemm_mfma_dual(
    const float* __restrict__ A,
    const unsigned short* __restrict__ FSh, const unsigned short* __restrict__ FSl,
    const unsigned short* __restrict__ FDh, const unsigned short* __restrict__ FDl,
    const float* __restrict__ bs_, const float* __restrict__ bd_,
    unsigned short* __restrict__ P, unsigned short* __restrict__ Q, int M) {
  const int tid = (int)threadIdx.x;
  const int w = tid >> 6;
  const int l = tid & 63;
  const int r0 = blockIdx.x * 64 + w * 16;
  const int arow = r0 + (l & 15);          // A-frag: row = lane&15
  const int koff = (l >> 4) << 3;          // A/B-frag: k = (lane>>4)*8 + j
  f32x4 accP[8] = {{0.f, 0.f, 0.f, 0.f}};
  f32x4 accQ[8] = {{0.f, 0.f, 0.f, 0.f}};
#pragma unroll
  for (int nb = 1; nb < 8; nb++) { accP[nb] = accP[0]; accQ[nb] = accQ[0]; }
  const bf16x8* fsh = (const bf16x8*)FSh;
  const bf16x8* fsl = (const bf16x8*)FSl;
  const bf16x8* fdh = (const bf16x8*)FDh;
  const bf16x8* fdl = (const bf16x8*)FDl;
#pragma unroll
  for (int ks = 0; ks < 4; ks++) {
    bf16x8 ahi, alo;
    if (arow < M) {
      const float* ap = A + (size_t)arow * 128 + ks * 32 + koff;
      float4 v0 = *(const float4*)ap;
      float4 v1 = *(const float4*)(ap + 4);
      float va[8] = {v0.x, v0.y, v0.z, v0.w, v1.x, v1.y, v1.z, v1.w};
#pragma unroll
      for (int j = 0; j < 8; j++) {
        unsigned short h = f32_to_bf16_rne(va[j]);
        ahi[j] = (short)h;
        alo[j] = (short)f32_to_bf16_rne(va[j] - bf16_bits_to_f32(h));
      }
    } else {
#pragma unroll
      for (int j = 0; j < 8; j++) { ahi[j] = 0; alo[j] = 0; }
    }
#pragma unroll
    for (int nb = 0; nb < 8; nb++) {
      int fi = (ks * 8 + nb) * 64 + l;
      bf16x8 bsh = fsh[fi];
      bf16x8 bsl = fsl[fi];
      bf16x8 bdh = fdh[fi];
      bf16x8 bdl = fdl[fi];
      accP[nb] = __builtin_amdgcn_mfma_f32_16x16x32_bf16(ahi, bsh, accP[nb], 0, 0, 0);
      accP[nb] = __builtin_amdgcn_mfma_f32_16x16x32_bf16(alo, bsh, accP[nb], 0, 0, 0);
      accP[nb] = __builtin_amdgcn_mfma_f32_16x16x32_bf16(ahi, bsl, accP[nb], 0, 0, 0);
      accQ[nb] = __builtin_amdgcn_mfma_f32_16x16x32_bf16(ahi, bdh, accQ[nb], 0, 0, 0);
      accQ[nb] = __builtin_amdgcn_mfma_f32_16x16x32_bf16(alo, bdh, accQ[nb], 0, 0, 0);
      accQ[nb] = __builtin_amdgcn_mfma_f32_16x16x32_bf16(ahi, bdl, accQ[nb], 0, 0, 0);
    }
  }
  // D-frag: col = lane&15, row = (lane>>4)*4 + reg   [m89-verified mapping]
  const int rbase = r0 + ((l >> 4) << 2);
  const int cl = l & 15;
#pragma unroll
  for (int nb = 0; nb < 8; nb++) {
    int col = nb * 16 + cl;
    float bP = bs_[col], bQ = bd_[col];
#pragma unroll
    for (int r = 0; r < 4; r++) {
      int grow = rbase + r;
      if (grow < M) {
        P[(size_t)grow * 128 + col] = f32_to_bf16_rne(accP[nb][r] + bP);
        Q[(size_t)grow * 128 + col] = f32_to_bf16_rne(accQ[nb][r] + bQ);
      }
    }
  }
}

// ---------------- GATv2 aggregation ----------------
// One wave per dst node, 4 edges per wave-step.
// lane = (es = lane>>4: edge slot 0..3, ls = lane&15: dim-lane).
// Lane owns dims ls*8..ls*8+7 (head = ls>>2) of its slot's edge: one dwordx4
// gather covers a full 256B feature row per slot (4 edges per VMEM instr).
// Per-slot online softmax (m init -1e30; invalid edges t=-2e30 -> ex=0, sc=1),
// flash-merged across slots at the end via xor-16/32 butterfly.
__global__ __launch_bounds__(256, 4) void gat_agg_kernel(
    const unsigned short* __restrict__ P,  // fs bf16 [N,128]
    const unsigned short* __restrict__ Q,  // fd bf16 [N,128]
    const float* __restrict__ attn,        // [128] = [H=4][D=32]
    const int* __restrict__ row_start,
    const int* __restrict__ src_sorted,
    float* __restrict__ out, int N, int do_relu) {
  int wave = (int)((blockIdx.x * blockDim.x + threadIdx.x) >> 6);
  int lane = (int)(threadIdx.x & 63);
  if (wave >= N) return;
  const int es = lane >> 4;
  const int ls = lane & 15;

  float fd[8], av[8];
  decode8(*(const uint4*)&Q[(size_t)wave * 128 + ls * 8], fd);
  {
    float4 A0 = *(const float4*)&attn[ls * 8];
    float4 A1 = *(const float4*)&attn[ls * 8 + 4];
    av[0] = A0.x; av[1] = A0.y; av[2] = A0.z; av[3] = A0.w;
    av[4] = A1.x; av[5] = A1.y; av[6] = A1.z; av[7] = A1.w;
  }
  const int s0 = row_start[wave], s1 = row_start[wave + 1];

  float m = -1e30f, den = 0.f;
  float acc[8];
#pragma unroll
  for (int d = 0; d < 8; d++) acc[d] = 0.f;

  // pipeline prologue: idx+row of chunk 0, idx of chunk 1
  int i0 = s0 + es;
  int idx_c = (i0 < s1) ? src_sorted[i0] : 0;
  uint4 row_n = *(const uint4*)&P[(size_t)idx_c * 128 + ls * 8];
  int i1 = i0 + 4;
  int idx_n = (i1 < s1) ? src_sorted[i1] : 0;

#pragma unroll 1
  for (int base = s0; base < s1; base += 4) {
    uint4 row = row_n;
    // issue row gather for chunk c+1 (idx already resolved)
    row_n = *(const uint4*)&P[(size_t)idx_n * 128 + ls * 8];
    // load idx for chunk c+2
    int i2 = base + 8 + es;
    idx_n = (i2 < s1) ? src_sorted[i2] : 0;
    // compute chunk c
    float c[8];
    decode8(row, c);
    float t = 0.f;
#pragma unroll
    for (int d = 0; d < 8; d++) {
      float x = c[d] + fd[d];
      x = fmaxf(x, NEG_SLOPE * x);          // exact leaky_relu for slope<1
      t = fmaf(x, av[d], t);
    }
    t += __shfl_xor(t, 1);                  // reduce over the head's 4 lanes
    t += __shfl_xor(t, 2);
    t = (base + es < s1) ? t : -2e30f;      // invalid slot -> ex=0, sc=1
    float mn = fmaxf(m, t);
    float sc = __expf(m - mn);
    float ex = __expf(t - mn);
    den = den * sc + ex;
#pragma unroll
    for (int d = 0; d < 8; d++) acc[d] = fmaf(acc[d], sc, ex * c[d]);
    m = mn;
  }

  // flash-merge the 4 slots (lanes differing in bits 4,5 share ls -> same dims/head)
  float M2 = m;
  M2 = fmaxf(M2, __shfl_xor(M2, 16));
  M2 = fmaxf(M2, __shfl_xor(M2, 32));
  float sc = __expf(m - M2);                // empty slot: exp(-1e30-M2)=0 (M2 finite)
  den *= sc;
#pragma unroll
  for (int d = 0; d < 8; d++) acc[d] *= sc;
  den += __shfl_xor(den, 16);
  den += __shfl_xor(den, 32);
#pragma unroll
  for (int d = 0; d < 8; d++) {
    acc[d] += __shfl_xor(acc[d], 16);
    acc[d] += __shfl_xor(acc[d], 32);
  }

  if (es == 0) {
    float invd = (s1 > s0) ? 1.f / den : 0.f;
    float o[8];
#pragma unroll
    for (int d = 0; d < 8; d++) {
      o[d] = acc[d] * invd;
      if (do_relu) o[d] = fmaxf(o[d], 0.f);
    }
    float* op = out + (size_t)wave * 128 + ls * 8;
    *(float4*)op = make_float4(o[0], o[1], o[2], o[3]);
    *(float4*)(op + 4) = make_float4(o[4], o[5], o[6], o[7]);
  }
}

// ---------------- link-prediction scores: one wave per query ----------------
__global__ __launch_bounds__(256) void edge_score_kernel(
    const float* __restrict__ H, const int* __restrict__ qs, const int* __restrict__ qd,
    float* __restrict__ out, int NQ) {
  int wave = (int)((blockIdx.x * blockDim.x + threadIdx.x) >> 6);
  int lane = (int)(threadIdx.x & 63);
  if (wave >= NQ) return;
  int a = qs[wave], b = qd[wave];
  float2 x = *(const float2*)&H[(size_t)a * 128 + lane * 2];
  float2 y = *(const float2*)&H[(size_t)b * 128 + lane * 2];
  float t = x.x * y.x + x.y * y.y;
#pragma unroll
  for (int mask = 1; mask < 64; mask <<= 1) t += __shfl_xor(t, mask, 64);
  if (lane == 0) out[wave] = 1.f / (1.f + __expf(-t));
}

// ---------------- launch ----------------
extern "C" void kernel_launch(void* const* d_in, const int* in_sizes, int n_in,
                              void* d_out, int out_size, void* d_ws, size_t ws_size,
                              hipStream_t stream) {
  const float* feat  = (const float*)d_in[0];
  const int*   esrc  = (const int*)d_in[1];
  const int*   edst  = (const int*)d_in[2];
  const int*   qsrc  = (const int*)d_in[3];
  const int*   qdst  = (const int*)d_in[4];
  const float* W1s   = (const float*)d_in[5];
  const float* b1s   = (const float*)d_in[6];
  const float* W1d   = (const float*)d_in[7];
  const float* b1d   = (const float*)d_in[8];
  const float* attn1 = (const float*)d_in[9];
  const float* W2s   = (const float*)d_in[10];
  const float* b2s   = (const float*)d_in[11];
  const float* W2d   = (const float*)d_in[12];
  const float* b2d   = (const float*)d_in[13];
  const float* attn2 = (const float*)d_in[14];
  float* out = (float*)d_out;

  const int N  = in_sizes[0] / 128;
  const int E  = in_sizes[1];
  const int NQ = in_sizes[3];
  const int NB = (N + 127) >> 7;   // 391 buckets

  char* p = (char*)d_ws;
  auto alloc = [&](size_t bytes) -> char* {
    char* r = p;
    p += (bytes + 255) & ~(size_t)255;
    return r;
  };
  unsigned short* P = (unsigned short*)alloc((size_t)N * 128 * 2);  // bf16
  unsigned short* Q = (unsigned short*)alloc((size_t)N * 128 * 2);  // bf16
  float* H          = (float*)alloc((size_t)N * 128 * 4);
  int*   row_start  = (int*)alloc((size_t)(N + 1) * 4);
  int*   src_sorted = (int*)alloc((size_t)E * 4);
  unsigned* pairs   = (unsigned*)alloc((size_t)E * 4);
  int*   bcnt       = (int*)alloc((size_t)(NBMAX + 1) * 4);
  int*   bbase      = (int*)alloc((size_t)(NBMAX + 1) * 4);
  int*   bcursor    = (int*)alloc((size_t)NBMAX * 4);
  unsigned short* FBhi = (unsigned short*)alloc(4 * 2048 * 8 * 2);  // 128KB
  unsigned short* FBlo = (unsigned short*)alloc(4 * 2048 * 8 * 2);

  // weight fragment pre-pack (independent of graph build)
  wfrag_kernel<<<32, 256, 0, stream>>>(W1s, W1d, W2s, W2d, FBhi, FBlo);

  // CSR build, bucketed (edges grouped by dst; within-node order arbitrary — sums only)
  hipMemsetAsync(bcnt, 0, (size_t)(NBMAX + 1) * 4, stream);
  bucket_hist_kernel<<<512, 256, 0, stream>>>(edst, bcnt, E, NB);
  bucket_scan_kernel<<<1, 512, 0, stream>>>(bcnt, bbase, bcursor, row_start, NB, N, E);
  pair_scatter_kernel<<<128, 256, 0, stream>>>(edst, esrc, bcursor, pairs, E, NB);
  csr_build_kernel<<<NB, 256, 0, stream>>>(pairs, bbase, row_start, src_sorted, N);

  const int gblocks = (N + 63) / 64;
  const int per_mat = 2048 * 8;  // ushorts per matrix in FB buffers

  // layer 1
  gemm_mfma_dual<<<gblocks, 256, 0, stream>>>(
      feat, FBhi + 0 * per_mat, FBlo + 0 * per_mat, FBhi + 1 * per_mat, FBlo + 1 * per_mat,
      b1s, b1d, P, Q, N);
  gat_agg_kernel<<<(N + 3) / 4, 256, 0, stream>>>(P, Q, attn1, row_start, src_sorted, H, N, 1);

  // layer 2
  gemm_mfma_dual<<<gblocks, 256, 0, stream>>>(
      H, FBhi + 2 * per_mat, FBlo + 2 * per_mat, FBhi + 3 * per_mat, FBlo + 3 * per_mat,
      b2s, b2d, P, Q, N);
  gat_agg_kernel<<<(N + 3) / 4, 256, 0, stream>>>(P, Q, attn2, row_start, src_sorted, H, N, 0);

  // scores
  edge_score_kernel<<<(NQ + 3) / 4, 256, 0, stream>>>(H, qsrc, qdst, out, NQ);
}